// Round 6
// baseline (378.634 us; speedup 1.0000x reference)
//
#include <hip/hip_runtime.h>
#include <math.h>

typedef _Float16 h16;
typedef _Float16 f16x8 __attribute__((ext_vector_type(8)));
typedef float f32x4 __attribute__((ext_vector_type(4)));

#define Bc 4
#define Hc 8
#define Tc 8192
#define Dc 64
#define NCc 64
#define WSZc 128
#define BHc (Bc*Hc)
#define MAXPc 16
#define OVFCAP 4095
#define OUT_ELEMS (16777216u)   // B*H*T*D

#define MFMA16(a,b,c) __builtin_amdgcn_mfma_f32_16x16x32_f16(a,b,c,0,0,0)

// ---------------------------------------------------------------------------
// Kernel 0: pack rel_weights[m][h][d] fp32 -> wh16[h][m][d] f16 (128 KB).
// Per-head 16 KB panel, L2/L3-resident, shared by 64 k_attn blocks.
// ---------------------------------------------------------------------------
__global__ __launch_bounds__(256) void k_wpack(const float* __restrict__ relw,
                                               h16* __restrict__ wh16) {
    int idx = blockIdx.x*256 + threadIdx.x;      // [0, 8192): 8 elems each
    int e = idx*8;
    int m = e >> 9, h = (e >> 6) & 7, d = e & 63;
    const float* src = relw + ((size_t)m*Hc + h)*Dc + d;
    float4 a = *(const float4*)src;
    float4 b = *(const float4*)(src + 4);
    f16x8 hv = {(h16)a.x,(h16)a.y,(h16)a.z,(h16)a.w,
                (h16)b.x,(h16)b.y,(h16)b.z,(h16)b.w};
    *(f16x8*)&wh16[((size_t)h*WSZc + m)*Dc + d] = hv;
}

// ---------------------------------------------------------------------------
// Kernel 1: dists[bh][c][t] = dot(l2norm(qk[bh][t]), means[h][c])  (fp32)
// plus commitment-loss raw sum atomically added into loss slot aux[1].
// ---------------------------------------------------------------------------
__global__ __launch_bounds__(256) void k_dists(const float* __restrict__ qk,
                                               const float* __restrict__ means,
                                               float* __restrict__ dists,
                                               float* __restrict__ loss_acc) {
    __shared__ float sm[NCc*Dc];       // means[h], 16 KB
    __shared__ float red[4];
    int tid = threadIdx.x;
    int blk = blockIdx.x;              // [0, BH*32)
    int bh  = blk >> 5;                // T/256 = 32 chunks per bh
    int chunk = blk & 31;
    int h = bh & (Hc-1);

    const float* mh = means + (size_t)h*NCc*Dc;
    for (int i = tid; i < NCc*Dc; i += 256) sm[i] = mh[i];
    __syncthreads();

    int t = chunk*256 + tid;
    const float* qrow = qk + ((size_t)bh*Tc + t)*Dc;
    float q[Dc];
    #pragma unroll
    for (int d = 0; d < Dc; d += 4) {
        float4 f = *(const float4*)(qrow + d);
        q[d] = f.x; q[d+1] = f.y; q[d+2] = f.z; q[d+3] = f.w;
    }
    float n2 = 0.f;
    #pragma unroll
    for (int d = 0; d < Dc; d++) n2 += q[d]*q[d];
    float nrm = sqrtf(n2);
    if (nrm < 1e-12f) nrm = 1e-12f;
    float inv = 1.0f/nrm;

    float best = -3.4e38f; int bc = 0;
    float* dbase = dists + ((size_t)bh*NCc)*Tc + (size_t)chunk*256 + tid;
    for (int c = 0; c < NCc; c++) {
        float acc = 0.f;
        const float* mc = sm + c*Dc;
        #pragma unroll
        for (int d = 0; d < Dc; d++) acc += q[d]*mc[d];
        float dv = acc*inv;
        dbase[(size_t)c*Tc] = dv;
        if (dv > best) { best = dv; bc = c; }   // strict > : first max wins
    }
    float ls = 0.f;
    const float* mb = sm + bc*Dc;
    #pragma unroll
    for (int d = 0; d < Dc; d++) {
        float diff = q[d]*inv - mb[d];
        ls += diff*diff;
    }
    float lf = ls;
    #pragma unroll
    for (int o = 32; o >= 1; o >>= 1) lf += __shfl_down(lf, o, 64);
    if ((tid & 63) == 0) red[tid >> 6] = lf;
    __syncthreads();
    if (tid == 0) atomicAdd(loss_acc, red[0]+red[1]+red[2]+red[3]);
}

// ---------------------------------------------------------------------------
// Kernel 2: per (bh,c) exact top-128 of 8192 (ties: lower index), sorted asc,
// with the inverse map (cnt/slots/aux) built in the same kernel.
// Keys live in REGISTERS (32/thread) — LDS is hist+scratch only (~18.9 KB).
// ---------------------------------------------------------------------------
__device__ inline unsigned blockScanIncl(unsigned v, volatile unsigned* wsum,
                                         int lane, int wid, unsigned* ptotal) {
    unsigned x = v;
    #pragma unroll
    for (int s = 1; s < 64; s <<= 1) {
        unsigned o = __shfl_up(x, s, 64);
        if (lane >= s) x += o;
    }
    if (lane == 63) wsum[wid] = x;
    __syncthreads();
    unsigned off = 0, tot = 0;
    #pragma unroll
    for (int w2 = 0; w2 < 4; w2++) {
        unsigned s2 = wsum[w2];
        if (w2 < wid) off += s2;
        tot += s2;
    }
    *ptotal = tot;
    return x + off;
}

__global__ __launch_bounds__(256, 6) void k_topk(const float* __restrict__ dists,
                                              int* __restrict__ indices,
                                              unsigned* __restrict__ cnt,
                                              unsigned short* __restrict__ slots,
                                              unsigned* __restrict__ aux) {
    __shared__ unsigned hist[4096];    // 16 KB
    __shared__ unsigned bmap[256];     // 1 KB (8192-bit selection bitmap)
    __shared__ unsigned eqbuf[256];    // 1 KB (tie candidates, rare path)
    __shared__ unsigned wsum[4];
    __shared__ unsigned sh_prefix;
    __shared__ int      sh_k, cnt_eq;

    int tid = threadIdx.x;
    int lane = tid & 63, wid = tid >> 6;
    int bhc = blockIdx.x, bh = bhc >> 6, c = bhc & 63;
    const float* dp = dists + (size_t)bhc*Tc;

    for (int i = tid; i < 4096; i += 256) hist[i] = 0u;
    if (tid == 0) { sh_k = WSZc; sh_prefix = 0u; cnt_eq = 0; }
    bmap[tid] = 0u;
    __syncthreads();

    // load 32 keys/thread into registers (float4-coalesced) + level-0 hist.
    // token for key[ch][j] is  t = ch*1024 + tid*4 + j.
    unsigned key[8][4];
    #pragma unroll
    for (int ch = 0; ch < 8; ch++) {
        float4 f = *(const float4*)(dp + ch*1024 + tid*4);
        float fv[4] = {f.x, f.y, f.z, f.w};
        #pragma unroll
        for (int j = 0; j < 4; j++) {
            unsigned u = __float_as_uint(fv[j]);
            u = (u & 0x80000000u) ? ~u : (u | 0x80000000u);  // order-preserving
            key[ch][j] = u;
            atomicAdd(&hist[u >> 20], 1u);
        }
    }
    __syncthreads();

    unsigned prefix = 0u; int k = WSZc;
    #pragma unroll
    for (int lvl = 0; lvl < 3; lvl++) {
        const int shift   = (lvl == 0) ? 20 : (lvl == 1 ? 8 : 0);
        const int nper    = (lvl == 2) ? 1 : 16;           // bins per thread
        const unsigned nbm = (lvl == 2) ? 255u : 4095u;    // bin mask
        if (lvl > 0) {
            // build filtered histogram for this level (register sweep)
            const unsigned maskH = (lvl == 1) ? 0xFFF00000u : 0xFFFFFF00u;
            for (int i = tid; i <= (int)nbm; i += 256) hist[i] = 0u;
            __syncthreads();
            #pragma unroll
            for (int ch = 0; ch < 8; ch++)
                #pragma unroll
                for (int j = 0; j < 4; j++) {
                    unsigned ky = key[ch][j];
                    if ((ky & maskH) == prefix)
                        atomicAdd(&hist[(ky >> shift) & nbm], 1u);
                }
            __syncthreads();
        }
        // parallel crossing-bin search (suffix = total - excl_ascending)
        int tBase = tid*nper;
        unsigned psum = 0;
        for (int i = 0; i < nper; i++) psum += hist[tBase + i];
        unsigned total;
        unsigned incl = blockScanIncl(psum, wsum, lane, wid, &total);
        unsigned beyond = total - incl;          // keys in bins strictly above
        unsigned suff   = beyond + psum;
        if (beyond < (unsigned)k && (unsigned)k <= suff) {
            unsigned run = beyond;
            for (int i = nper - 1; i >= 0; i--) {
                unsigned hb = hist[tBase + i];
                run += hb;
                if (run >= (unsigned)k) {
                    sh_prefix = prefix | ((unsigned)(tBase + i) << shift);
                    sh_k = k - (int)(run - hb);
                    break;
                }
            }
        }
        __syncthreads();
        prefix = sh_prefix; k = sh_k;
        __syncthreads();
    }
    unsigned Kthr = prefix;    // exact 32-bit threshold key
    int kEq = k;               // # of threshold-equal keys to take (lowest idx)

    // collect: strict-greater -> bitmap; equal -> eqbuf (register sweep)
    #pragma unroll
    for (int ch = 0; ch < 8; ch++)
        #pragma unroll
        for (int j = 0; j < 4; j++) {
            unsigned ky = key[ch][j];
            int t = ch*1024 + tid*4 + j;
            if (ky > Kthr) atomicOr(&bmap[t >> 5], 1u << (t & 31));
            else if (ky == Kthr) {
                int p = atomicAdd(&cnt_eq, 1);
                if (p < 256) eqbuf[p] = (unsigned)t;
            }
        }
    __syncthreads();
    if (cnt_eq == kEq) {       // common path: every equal key is selected
        if (tid < kEq) {
            unsigned t = eqbuf[tid];
            atomicOr(&bmap[t >> 5], 1u << (t & 31));
        }
    } else {                   // rare: sort ties, take lowest kEq indices
        int ce = cnt_eq < 256 ? cnt_eq : 256;
        if (tid >= ce) eqbuf[tid] = 0xFFFFFFFFu;
        __syncthreads();
        for (int k2 = 2; k2 <= 256; k2 <<= 1) {
            for (int j = k2 >> 1; j >= 1; j >>= 1) {
                int i = tid, ixj = i ^ j;
                if (ixj > i) {
                    bool up = ((i & k2) == 0);
                    unsigned a = eqbuf[i], b = eqbuf[ixj];
                    if ((a > b) == up) { eqbuf[i] = b; eqbuf[ixj] = a; }
                }
                __syncthreads();
            }
        }
        if (tid < kEq) {
            unsigned t = eqbuf[tid];
            atomicOr(&bmap[t >> 5], 1u << (t & 31));
        }
    }
    __syncthreads();

    // rank via popcount prefix: indices come out sorted ascending by token
    unsigned w = bmap[tid];
    int pc = __popc(w);
    unsigned total2;
    unsigned incl2 = blockScanIncl((unsigned)pc, wsum, lane, wid, &total2);
    int pos = (int)(incl2 - pc);     // exclusive prefix = output position
    while (w) {
        int b = __ffs(w) - 1; w &= w - 1;
        int t = tid*32 + b;
        indices[(size_t)bhc*WSZc + pos] = t;
        // fused inverse map
        unsigned row = ((unsigned)bh << 13) + (unsigned)t;
        unsigned p2 = atomicAdd(&cnt[row], 1u);
        if (p2 < MAXPc) slots[(size_t)row*MAXPc + p2] = (unsigned short)(c*128 + pos);
        else {
            unsigned o = atomicAdd(&aux[0], 1u);
            if (o < OVFCAP) aux[2+o] = (unsigned)(bhc*WSZc + pos);
        }
        pos++;
    }
}

// ---------------------------------------------------------------------------
// Kernel 3: per (bh,c) fused attention via f16 MFMA (16x16x32).
// (256,3): retry of the 3-block cap now that A1's operand pressure is gone —
// wh16 f16 B-frags are 4 regs each (was 16 fp32 regs/tile in R2-R4, which
// spilled). Peak demand ~64 AGPR + ~70 VGPR ~= 140 <= 168 cap.
// LDS 53,760 B x 3 = 161,280 <= 160 KiB. Spill signature: WRITE_SIZE > 65.5MB.
// Wave w owns rows [32w, 32w+32). shift(rel)[i][j] = rel[i][127+j-i], j<=i.
// ---------------------------------------------------------------------------
__global__ __launch_bounds__(256, 3) void k_attn(const float* __restrict__ qk,
                                                 const float* __restrict__ v,
                                                 const h16* __restrict__ wh16,
                                                 const int* __restrict__ indices,
                                                 float* __restrict__ bo) {
    __shared__ __align__(16) h16 qv[128*72];      // 18432 B: q f16, later v^T[64][136]
    __shared__ __align__(16) h16 sp[128*136];     // 34816 B: rel scatter, then P
    __shared__ float sinv[128];

    int tid = threadIdx.x;
    int bid = blockIdx.x;
    int bhc = ((bid & 7) << 8) | (bid >> 3);      // XCD-chunked (bijective, 2048=8*256)
    int bh = bhc >> 6, h = bh & (Hc-1);
    int lane = tid & 63, wid = tid >> 6;
    int quad = lane >> 4, lj = lane & 15;
    int i0 = wid*32;

    // own gather row (q and v use the same row index tid>>1)
    int myIdx = indices[(size_t)bhc*WSZc + (tid >> 1)];

    {   // stage q (gathered) fp32->f16; sinv on the fly
        int i = tid >> 1, hf = tid & 1;
        const float* qrow = qk + ((size_t)bh*Tc + myIdx)*Dc + hf*32;
        float n2 = 0.f;
        #pragma unroll
        for (int k8 = 0; k8 < 4; k8++) {
            float4 a = *(const float4*)(qrow + k8*8);
            float4 b = *(const float4*)(qrow + k8*8 + 4);
            n2 += a.x*a.x + a.y*a.y + a.z*a.z + a.w*a.w
                + b.x*b.x + b.y*b.y + b.z*b.z + b.w*b.w;
            f16x8 hq = {(h16)a.x,(h16)a.y,(h16)a.z,(h16)a.w,
                        (h16)b.x,(h16)b.y,(h16)b.z,(h16)b.w};
            *(f16x8*)&qv[i*72 + hf*32 + k8*8] = hq;
        }
        n2 += __shfl_xor(n2, 1, 64);
        if (hf == 0) {
            float nr = sqrtf(n2); if (nr < 1e-12f) nr = 1e-12f;
            sinv[i] = 0.125f / nr;
        }
    }
    __syncthreads();   // B1: q + sinv visible

    // A1: REL[i][m] = q_i . w_m (K=64), w from pre-packed f16 panel (L2-hot).
    // Only m >= 127 - i_max matters: wave w needs nt >= 6-2*w.
    int ntMin = 6 - 2*wid;
    {
        f32x4 accR[2][8];
        #pragma unroll
        for (int mt = 0; mt < 2; mt++)
            #pragma unroll
            for (int nt = 0; nt < 8; nt++)
                #pragma unroll
                for (int e = 0; e < 4; e++) accR[mt][nt][e] = 0.f;
        const h16* whp = wh16 + (size_t)h*WSZc*Dc;   // [m][d] f16
        #pragma unroll
        for (int k0 = 0; k0 < 64; k0 += 32) {
            f16x8 a0 = *(const f16x8*)&qv[(i0 + lj)*72 + k0 + quad*8];
            f16x8 a1 = *(const f16x8*)&qv[(i0 + 16 + lj)*72 + k0 + quad*8];
            #pragma unroll
            for (int nt = 0; nt < 8; nt++) {
                if (nt < ntMin) continue;          // wave-uniform skip
                f16x8 bf = *(const f16x8*)&whp[(size_t)(nt*16 + lj)*Dc + k0 + quad*8];
                accR[0][nt] = MFMA16(a0, bf, accR[0][nt]);
                accR[1][nt] = MFMA16(a1, bf, accR[1][nt]);
            }
        }
        // scatter *0.125 into sp[i][m-127+i]; covers exactly j in [0, i]
        #pragma unroll
        for (int mt = 0; mt < 2; mt++)
            #pragma unroll
            for (int nt = 0; nt < 8; nt++) {
                if (nt < ntMin) continue;
                #pragma unroll
                for (int r = 0; r < 4; r++) {
                    int i = i0 + mt*16 + quad*4 + r;
                    int j = nt*16 + lj - 127 + i;
                    if (j >= 0) sp[i*136 + j] = (h16)(accR[mt][nt][r] * 0.125f);
                }
            }
    }

    // prefetch v rows (gathered) as f16 — 16 VGPRs, consumed after S2
    f16x8 vh[4];
    {
        int hf = tid & 1;
        const float* vrow = v + ((size_t)bh*Tc + myIdx)*Dc + hf*32;
        #pragma unroll
        for (int r = 0; r < 4; r++) {
            float4 a = *(const float4*)(vrow + r*8);
            float4 b = *(const float4*)(vrow + r*8 + 4);
            f16x8 hv = {(h16)a.x,(h16)a.y,(h16)a.z,(h16)a.w,
                        (h16)b.x,(h16)b.y,(h16)b.z,(h16)b.w};
            vh[r] = hv;
        }
    }

    // A2: S = Q.Q^T
    f32x4 accS[2][8];
    #pragma unroll
    for (int mt = 0; mt < 2; mt++)
        #pragma unroll
        for (int nt = 0; nt < 8; nt++)
            #pragma unroll
            for (int e = 0; e < 4; e++) accS[mt][nt][e] = 0.f;
    #pragma unroll
    for (int k0 = 0; k0 < 64; k0 += 32) {
        f16x8 a0 = *(const f16x8*)&qv[(i0 + lj)*72 + k0 + quad*8];
        f16x8 a1 = *(const f16x8*)&qv[(i0 + 16 + lj)*72 + k0 + quad*8];
        #pragma unroll
        for (int nt = 0; nt < 8; nt++) {
            f16x8 bf = *(const f16x8*)&qv[(nt*16 + lj)*72 + k0 + quad*8];
            accS[0][nt] = MFMA16(a0, bf, accS[0][nt]);
            accS[1][nt] = MFMA16(a1, bf, accS[1][nt]);
        }
    }
    __syncthreads();   // S2: all qv(q) reads done -> region reusable for v^T

    #pragma unroll
    for (int nt = 0; nt < 8; nt++) {   // scale + rel (j<=i, else 0) + diag mask
        int j = nt*16 + lj;
        float sj = sinv[j];
        #pragma unroll
        for (int mt = 0; mt < 2; mt++)
            #pragma unroll
            for (int r = 0; r < 4; r++) {
                int i = i0 + mt*16 + quad*4 + r;
                float rl = (j <= i) ? (float)sp[i*136 + j] : 0.f;
                float s = accS[mt][nt][r]*sj + rl;
                accS[mt][nt][r] = (i == j) ? -50000.0f : s;
            }
    }
    #pragma unroll
    for (int mt = 0; mt < 2; mt++)      // softmax (rows live in 16-lane quads)
        #pragma unroll
        for (int r = 0; r < 4; r++) {
            float mx = accS[mt][0][r];
            #pragma unroll
            for (int nt = 1; nt < 8; nt++) mx = fmaxf(mx, accS[mt][nt][r]);
            #pragma unroll
            for (int st = 1; st <= 8; st <<= 1) mx = fmaxf(mx, __shfl_xor(mx, st, 64));
            float sum = 0.f;
            #pragma unroll
            for (int nt = 0; nt < 8; nt++) {
                float e = __expf(accS[mt][nt][r] - mx);
                accS[mt][nt][r] = e; sum += e;
            }
            #pragma unroll
            for (int st = 1; st <= 8; st <<= 1) sum += __shfl_xor(sum, st, 64);
            float inv = 1.0f/sum;
            #pragma unroll
            for (int nt = 0; nt < 8; nt++) accS[mt][nt][r] *= inv;
        }
    #pragma unroll
    for (int mt = 0; mt < 2; mt++)      // write P (f16) to sp (own rows)
        #pragma unroll
        for (int nt = 0; nt < 8; nt++)
            #pragma unroll
            for (int r = 0; r < 4; r++) {
                int i = i0 + mt*16 + quad*4 + r;
                sp[i*136 + nt*16 + lj] = (h16)accS[mt][nt][r];
            }
    {   // store v^T into qv region: vt[d][j], stride 136 (64*136 <= 128*72)
        h16* vt = qv;
        int j = tid >> 1, hf = tid & 1;
        #pragma unroll
        for (int r = 0; r < 4; r++) {
            int d0 = hf*32 + r*8;
            #pragma unroll
            for (int e = 0; e < 8; e++)
                vt[(d0+e)*136 + j] = vh[r][e];
        }
    }
    __syncthreads();   // S3: P + v^T visible

    // O = P.V (K=128)
    f32x4 accO[2][4];
    #pragma unroll
    for (int mt = 0; mt < 2; mt++)
        #pragma unroll
        for (int nt = 0; nt < 4; nt++)
            #pragma unroll
            for (int e = 0; e < 4; e++) accO[mt][nt][e] = 0.f;
    #pragma unroll
    for (int k0 = 0; k0 < 128; k0 += 32) {
        f16x8 a0 = *(const f16x8*)&sp[(i0 + lj)*136 + k0 + quad*8];
        f16x8 a1 = *(const f16x8*)&sp[(i0 + 16 + lj)*136 + k0 + quad*8];
        #pragma unroll
        for (int nt = 0; nt < 4; nt++) {
            f16x8 bf = *(const f16x8*)&qv[(nt*16 + lj)*136 + k0 + quad*8];
            accO[0][nt] = MFMA16(a0, bf, accO[0][nt]);
            accO[1][nt] = MFMA16(a1, bf, accO[1][nt]);
        }
    }
    #pragma unroll
    for (int mt = 0; mt < 2; mt++)
        #pragma unroll
        for (int nt = 0; nt < 4; nt++)
            #pragma unroll
            for (int r = 0; r < 4; r++) {
                int i = i0 + mt*16 + quad*4 + r;
                bo[((size_t)bhc*WSZc + i)*Dc + nt*16 + lj] = accO[mt][nt][r];
            }
}

// ---------------------------------------------------------------------------
// Kernel 4: out[bh,t,:] = (sum of its bo rows + rare ovf) / (cnt+EPS); loss.
// ---------------------------------------------------------------------------
__global__ __launch_bounds__(256) void k_final(const float* __restrict__ bo,
                                               const unsigned short* __restrict__ slots,
                                               const unsigned* __restrict__ cnt,
                                               const int* __restrict__ indices,
                                               const unsigned* __restrict__ aux,
                                               float* __restrict__ out) {
    int row  = blockIdx.x*4 + (threadIdx.x >> 6);   // [0, BH*T)
    int lane = threadIdx.x & 63;
    unsigned c = cnt[row];
    unsigned m = c < MAXPc ? c : MAXPc;
    int bh = row >> 13;
    float acc = 0.f;
    const unsigned short* sl = slots + (size_t)row*MAXPc;
    for (unsigned p = 0; p < m; p++)
        acc += bo[(((size_t)bh << 13) + sl[p])*Dc + lane];
    if (c > MAXPc) {   // astronomically rare
        unsigned n = aux[0]; if (n > OVFCAP) n = OVFCAP;
        int tok = row & 8191;
        for (unsigned q = 0; q < n; q++) {
            unsigned e = aux[2+q];
            if ((int)(e >> 13) == bh && indices[e] == tok)
                acc += bo[(((size_t)bh << 13) + (e & 8191))*Dc + lane];
        }
    }
    out[(size_t)row*Dc + lane] = acc * (1.0f/((float)c + 1e-5f));
    if (row == 0 && lane == 0)
        out[OUT_ELEMS] = ((const float*)aux)[1] * (float)(1e-4 / 16777216.0);
}

extern "C" void kernel_launch(void* const* d_in, const int* in_sizes, int n_in,
                              void* d_out, int out_size, void* d_ws, size_t ws_size,
                              hipStream_t stream) {
    const float* qk    = (const float*)d_in[0];
    const float* v     = (const float*)d_in[1];
    const float* means = (const float*)d_in[2];
    const float* relw  = (const float*)d_in[3];
    float* out = (float*)d_out;
    char*  ws  = (char*)d_ws;

    // workspace layout (bo aliases dists: dists dead after k_topk)
    size_t off = 0;
    float* dists = (float*)(ws + off);
    float* bo    = dists;
    off += (size_t)BHc*NCc*Tc*4;                                           // 64 MB
    int* indices = (int*)(ws + off); off += (size_t)BHc*NCc*WSZc*4;        // 1 MB
    unsigned* cnt = (unsigned*)(ws + off); off += (size_t)BHc*Tc*4;        // 1 MB
    unsigned* aux = (unsigned*)(ws + off); off += (size_t)(2+OVFCAP)*4;    // 16 KB
    unsigned short* slots = (unsigned short*)(ws + off);
    off += (size_t)BHc*Tc*MAXPc*2;                                         // 8 MB
    h16* wh16 = (h16*)(ws + off); off += (size_t)WSZc*Hc*Dc*2;             // 128 KB

    // single memset covers cnt + aux (adjacent)
    hipMemsetAsync(cnt, 0, (size_t)BHc*Tc*4 + (size_t)(2+OVFCAP)*4, stream);

    k_wpack <<<32,           256, 0, stream>>>(relw, wh16);
    k_dists <<<BHc*(Tc/256), 256, 0, stream>>>(qk, means, dists, (float*)aux + 1);
    k_topk  <<<BHc*NCc,      256, 0, stream>>>(dists, indices, cnt, slots, aux);
    k_attn  <<<BHc*NCc,      256, 0, stream>>>(qk, v, wh16, indices, bo);
    k_final <<<BHc*Tc/4,     256, 0, stream>>>(bo, slots, cnt, indices, aux, out);
}

// Round 7
// 363.394 us; speedup vs baseline: 1.0419x; 1.0419x over previous
//
#include <hip/hip_runtime.h>
#include <math.h>

typedef _Float16 h16;
typedef _Float16 f16x8 __attribute__((ext_vector_type(8)));
typedef float f32x4 __attribute__((ext_vector_type(4)));

#define Bc 4
#define Hc 8
#define Tc 8192
#define Dc 64
#define NCc 64
#define WSZc 128
#define BHc (Bc*Hc)
#define MAXPc 16
#define OVFCAP 4095
#define OUT_ELEMS (16777216u)   // B*H*T*D

#define MFMA16(a,b,c) __builtin_amdgcn_mfma_f32_16x16x32_f16(a,b,c,0,0,0)

// ---------------------------------------------------------------------------
// Kernel 0: pack rel_weights[m][h][d] fp32 -> wh16[h][m][d] f16 (128 KB).
// Per-head 16 KB panel, L2/L3-resident, shared by 64 k_attn blocks.
// ---------------------------------------------------------------------------
__global__ __launch_bounds__(256) void k_wpack(const float* __restrict__ relw,
                                               h16* __restrict__ wh16) {
    int idx = blockIdx.x*256 + threadIdx.x;      // [0, 8192): 8 elems each
    int e = idx*8;
    int m = e >> 9, h = (e >> 6) & 7, d = e & 63;
    const float* src = relw + ((size_t)m*Hc + h)*Dc + d;
    float4 a = *(const float4*)src;
    float4 b = *(const float4*)(src + 4);
    f16x8 hv = {(h16)a.x,(h16)a.y,(h16)a.z,(h16)a.w,
                (h16)b.x,(h16)b.y,(h16)b.z,(h16)b.w};
    *(f16x8*)&wh16[((size_t)h*WSZc + m)*Dc + d] = hv;
}

// ---------------------------------------------------------------------------
// Kernel 1: dists[bh][c][t] = dot(l2norm(qk[bh][t]), means[h][c])  (fp32)
// plus commitment-loss raw sum atomically added into loss slot aux[1].
// ---------------------------------------------------------------------------
__global__ __launch_bounds__(256) void k_dists(const float* __restrict__ qk,
                                               const float* __restrict__ means,
                                               float* __restrict__ dists,
                                               float* __restrict__ loss_acc) {
    __shared__ float sm[NCc*Dc];       // means[h], 16 KB
    __shared__ float red[4];
    int tid = threadIdx.x;
    int blk = blockIdx.x;              // [0, BH*32)
    int bh  = blk >> 5;                // T/256 = 32 chunks per bh
    int chunk = blk & 31;
    int h = bh & (Hc-1);

    const float* mh = means + (size_t)h*NCc*Dc;
    for (int i = tid; i < NCc*Dc; i += 256) sm[i] = mh[i];
    __syncthreads();

    int t = chunk*256 + tid;
    const float* qrow = qk + ((size_t)bh*Tc + t)*Dc;
    float q[Dc];
    #pragma unroll
    for (int d = 0; d < Dc; d += 4) {
        float4 f = *(const float4*)(qrow + d);
        q[d] = f.x; q[d+1] = f.y; q[d+2] = f.z; q[d+3] = f.w;
    }
    float n2 = 0.f;
    #pragma unroll
    for (int d = 0; d < Dc; d++) n2 += q[d]*q[d];
    float nrm = sqrtf(n2);
    if (nrm < 1e-12f) nrm = 1e-12f;
    float inv = 1.0f/nrm;

    float best = -3.4e38f; int bc = 0;
    float* dbase = dists + ((size_t)bh*NCc)*Tc + (size_t)chunk*256 + tid;
    for (int c = 0; c < NCc; c++) {
        float acc = 0.f;
        const float* mc = sm + c*Dc;
        #pragma unroll
        for (int d = 0; d < Dc; d++) acc += q[d]*mc[d];
        float dv = acc*inv;
        dbase[(size_t)c*Tc] = dv;
        if (dv > best) { best = dv; bc = c; }   // strict > : first max wins
    }
    float ls = 0.f;
    const float* mb = sm + bc*Dc;
    #pragma unroll
    for (int d = 0; d < Dc; d++) {
        float diff = q[d]*inv - mb[d];
        ls += diff*diff;
    }
    float lf = ls;
    #pragma unroll
    for (int o = 32; o >= 1; o >>= 1) lf += __shfl_down(lf, o, 64);
    if ((tid & 63) == 0) red[tid >> 6] = lf;
    __syncthreads();
    if (tid == 0) atomicAdd(loss_acc, red[0]+red[1]+red[2]+red[3]);
}

// ---------------------------------------------------------------------------
// Kernel 2: per (bh,c) exact top-128 of 8192 (ties: lower index), sorted asc,
// with the inverse map (cnt/slots/aux) built in the same kernel.
// Keys live in REGISTERS (32/thread) — LDS is hist+scratch only (~18.9 KB).
// ---------------------------------------------------------------------------
__device__ inline unsigned blockScanIncl(unsigned v, volatile unsigned* wsum,
                                         int lane, int wid, unsigned* ptotal) {
    unsigned x = v;
    #pragma unroll
    for (int s = 1; s < 64; s <<= 1) {
        unsigned o = __shfl_up(x, s, 64);
        if (lane >= s) x += o;
    }
    if (lane == 63) wsum[wid] = x;
    __syncthreads();
    unsigned off = 0, tot = 0;
    #pragma unroll
    for (int w2 = 0; w2 < 4; w2++) {
        unsigned s2 = wsum[w2];
        if (w2 < wid) off += s2;
        tot += s2;
    }
    *ptotal = tot;
    return x + off;
}

__global__ __launch_bounds__(256, 6) void k_topk(const float* __restrict__ dists,
                                              int* __restrict__ indices,
                                              unsigned* __restrict__ cnt,
                                              unsigned short* __restrict__ slots,
                                              unsigned* __restrict__ aux) {
    __shared__ unsigned hist[4096];    // 16 KB
    __shared__ unsigned bmap[256];     // 1 KB (8192-bit selection bitmap)
    __shared__ unsigned eqbuf[256];    // 1 KB (tie candidates, rare path)
    __shared__ unsigned wsum[4];
    __shared__ unsigned sh_prefix;
    __shared__ int      sh_k, cnt_eq;

    int tid = threadIdx.x;
    int lane = tid & 63, wid = tid >> 6;
    int bhc = blockIdx.x, bh = bhc >> 6, c = bhc & 63;
    const float* dp = dists + (size_t)bhc*Tc;

    for (int i = tid; i < 4096; i += 256) hist[i] = 0u;
    if (tid == 0) { sh_k = WSZc; sh_prefix = 0u; cnt_eq = 0; }
    bmap[tid] = 0u;
    __syncthreads();

    // load 32 keys/thread into registers (float4-coalesced) + level-0 hist.
    // token for key[ch][j] is  t = ch*1024 + tid*4 + j.
    unsigned key[8][4];
    #pragma unroll
    for (int ch = 0; ch < 8; ch++) {
        float4 f = *(const float4*)(dp + ch*1024 + tid*4);
        float fv[4] = {f.x, f.y, f.z, f.w};
        #pragma unroll
        for (int j = 0; j < 4; j++) {
            unsigned u = __float_as_uint(fv[j]);
            u = (u & 0x80000000u) ? ~u : (u | 0x80000000u);  // order-preserving
            key[ch][j] = u;
            atomicAdd(&hist[u >> 20], 1u);
        }
    }
    __syncthreads();

    unsigned prefix = 0u; int k = WSZc;
    #pragma unroll
    for (int lvl = 0; lvl < 3; lvl++) {
        const int shift   = (lvl == 0) ? 20 : (lvl == 1 ? 8 : 0);
        const int nper    = (lvl == 2) ? 1 : 16;           // bins per thread
        const unsigned nbm = (lvl == 2) ? 255u : 4095u;    // bin mask
        if (lvl > 0) {
            // build filtered histogram for this level (register sweep)
            const unsigned maskH = (lvl == 1) ? 0xFFF00000u : 0xFFFFFF00u;
            for (int i = tid; i <= (int)nbm; i += 256) hist[i] = 0u;
            __syncthreads();
            #pragma unroll
            for (int ch = 0; ch < 8; ch++)
                #pragma unroll
                for (int j = 0; j < 4; j++) {
                    unsigned ky = key[ch][j];
                    if ((ky & maskH) == prefix)
                        atomicAdd(&hist[(ky >> shift) & nbm], 1u);
                }
            __syncthreads();
        }
        // parallel crossing-bin search (suffix = total - excl_ascending)
        int tBase = tid*nper;
        unsigned psum = 0;
        for (int i = 0; i < nper; i++) psum += hist[tBase + i];
        unsigned total;
        unsigned incl = blockScanIncl(psum, wsum, lane, wid, &total);
        unsigned beyond = total - incl;          // keys in bins strictly above
        unsigned suff   = beyond + psum;
        if (beyond < (unsigned)k && (unsigned)k <= suff) {
            unsigned run = beyond;
            for (int i = nper - 1; i >= 0; i--) {
                unsigned hb = hist[tBase + i];
                run += hb;
                if (run >= (unsigned)k) {
                    sh_prefix = prefix | ((unsigned)(tBase + i) << shift);
                    sh_k = k - (int)(run - hb);
                    break;
                }
            }
        }
        __syncthreads();
        prefix = sh_prefix; k = sh_k;
        __syncthreads();
    }
    unsigned Kthr = prefix;    // exact 32-bit threshold key
    int kEq = k;               // # of threshold-equal keys to take (lowest idx)

    // collect: strict-greater -> bitmap; equal -> eqbuf (register sweep)
    #pragma unroll
    for (int ch = 0; ch < 8; ch++)
        #pragma unroll
        for (int j = 0; j < 4; j++) {
            unsigned ky = key[ch][j];
            int t = ch*1024 + tid*4 + j;
            if (ky > Kthr) atomicOr(&bmap[t >> 5], 1u << (t & 31));
            else if (ky == Kthr) {
                int p = atomicAdd(&cnt_eq, 1);
                if (p < 256) eqbuf[p] = (unsigned)t;
            }
        }
    __syncthreads();
    if (cnt_eq == kEq) {       // common path: every equal key is selected
        if (tid < kEq) {
            unsigned t = eqbuf[tid];
            atomicOr(&bmap[t >> 5], 1u << (t & 31));
        }
    } else {                   // rare: sort ties, take lowest kEq indices
        int ce = cnt_eq < 256 ? cnt_eq : 256;
        if (tid >= ce) eqbuf[tid] = 0xFFFFFFFFu;
        __syncthreads();
        for (int k2 = 2; k2 <= 256; k2 <<= 1) {
            for (int j = k2 >> 1; j >= 1; j >>= 1) {
                int i = tid, ixj = i ^ j;
                if (ixj > i) {
                    bool up = ((i & k2) == 0);
                    unsigned a = eqbuf[i], b = eqbuf[ixj];
                    if ((a > b) == up) { eqbuf[i] = b; eqbuf[ixj] = a; }
                }
                __syncthreads();
            }
        }
        if (tid < kEq) {
            unsigned t = eqbuf[tid];
            atomicOr(&bmap[t >> 5], 1u << (t & 31));
        }
    }
    __syncthreads();

    // rank via popcount prefix: indices come out sorted ascending by token
    unsigned w = bmap[tid];
    int pc = __popc(w);
    unsigned total2;
    unsigned incl2 = blockScanIncl((unsigned)pc, wsum, lane, wid, &total2);
    int pos = (int)(incl2 - pc);     // exclusive prefix = output position
    while (w) {
        int b = __ffs(w) - 1; w &= w - 1;
        int t = tid*32 + b;
        indices[(size_t)bhc*WSZc + pos] = t;
        // fused inverse map
        unsigned row = ((unsigned)bh << 13) + (unsigned)t;
        unsigned p2 = atomicAdd(&cnt[row], 1u);
        if (p2 < MAXPc) slots[(size_t)row*MAXPc + p2] = (unsigned short)(c*128 + pos);
        else {
            unsigned o = atomicAdd(&aux[0], 1u);
            if (o < OVFCAP) aux[2+o] = (unsigned)(bhc*WSZc + pos);
        }
        pos++;
    }
}

// ---------------------------------------------------------------------------
// Kernel 3: per (bh,c) fused attention via f16 MFMA (16x16x32).
// 512 threads, 8 waves, 16 ROWS/WAVE: per-thread S-state halves to 32 regs
// (R2-R6 lesson: 32 rows/wave needs ~190+ regs -> spills under any cap<=168).
// (512,4): cap 128 incl AGPR -> 2 blocks/CU = 16 waves (2x R5 concurrency).
// LDS 53,760 B unchanged. Spill signature to watch: WRITE_SIZE > 65.5 MB.
// Wave w owns rows [16w, 16w+16). shift(rel)[i][j] = rel[i][127+j-i], j<=i.
// ---------------------------------------------------------------------------
__global__ __launch_bounds__(512, 4) void k_attn(const float* __restrict__ qk,
                                                 const float* __restrict__ v,
                                                 const h16* __restrict__ wh16,
                                                 const int* __restrict__ indices,
                                                 float* __restrict__ bo) {
    __shared__ __align__(16) h16 qv[128*72];      // 18432 B: q f16, later v^T[64][136]
    __shared__ __align__(16) h16 sp[128*136];     // 34816 B: rel scatter, then P
    __shared__ float sinv[128];

    int tid = threadIdx.x;                        // 0..511
    int bid = blockIdx.x;
    int bhc = ((bid & 7) << 8) | (bid >> 3);      // XCD-chunked (bijective, 2048=8*256)
    int bh = bhc >> 6, h = bh & (Hc-1);
    int lane = tid & 63, wid = tid >> 6;          // wid 0..7
    int quad = lane >> 4, lj = lane & 15;
    int i0 = wid*16;

    // staging role: 4 threads per row, 16 floats each
    int row4 = tid >> 2, hf4 = tid & 3;
    int myIdx = indices[(size_t)bhc*WSZc + row4];

    {   // stage q (gathered) fp32->f16; sinv on the fly
        const float* qrow = qk + ((size_t)bh*Tc + myIdx)*Dc + hf4*16;
        float n2 = 0.f;
        #pragma unroll
        for (int k8 = 0; k8 < 2; k8++) {
            float4 a = *(const float4*)(qrow + k8*8);
            float4 b = *(const float4*)(qrow + k8*8 + 4);
            n2 += a.x*a.x + a.y*a.y + a.z*a.z + a.w*a.w
                + b.x*b.x + b.y*b.y + b.z*b.z + b.w*b.w;
            f16x8 hq = {(h16)a.x,(h16)a.y,(h16)a.z,(h16)a.w,
                        (h16)b.x,(h16)b.y,(h16)b.z,(h16)b.w};
            *(f16x8*)&qv[row4*72 + hf4*16 + k8*8] = hq;
        }
        n2 += __shfl_xor(n2, 1, 64);
        n2 += __shfl_xor(n2, 2, 64);
        if (hf4 == 0) {
            float nr = sqrtf(n2); if (nr < 1e-12f) nr = 1e-12f;
            sinv[row4] = 0.125f / nr;
        }
    }
    __syncthreads();   // B1: q + sinv visible

    // A1: REL[i][m] = q_i . w_m (K=64), w from pre-packed f16 panel (L2-hot).
    // Rows [16w,16w+16): only nt >= 7-w produce any j>=0.
    int ntMin = 7 - wid;
    {
        f32x4 accR[8];
        #pragma unroll
        for (int nt = 0; nt < 8; nt++)
            #pragma unroll
            for (int e = 0; e < 4; e++) accR[nt][e] = 0.f;
        const h16* whp = wh16 + (size_t)h*WSZc*Dc;   // [m][d] f16
        #pragma unroll
        for (int k0 = 0; k0 < 64; k0 += 32) {
            f16x8 a = *(const f16x8*)&qv[(i0 + lj)*72 + k0 + quad*8];
            #pragma unroll
            for (int nt = 0; nt < 8; nt++) {
                if (nt < ntMin) continue;          // wave-uniform skip
                f16x8 bf = *(const f16x8*)&whp[(size_t)(nt*16 + lj)*Dc + k0 + quad*8];
                accR[nt] = MFMA16(a, bf, accR[nt]);
            }
        }
        // scatter *0.125 into sp[i][m-127+i]; covers exactly j in [0, i] (own rows)
        #pragma unroll
        for (int nt = 0; nt < 8; nt++) {
            if (nt < ntMin) continue;
            #pragma unroll
            for (int r = 0; r < 4; r++) {
                int i = i0 + quad*4 + r;
                int j = nt*16 + lj - 127 + i;
                if (j >= 0) sp[i*136 + j] = (h16)(accR[nt][r] * 0.125f);
            }
        }
    }

    // prefetch v rows (gathered) as f16 — 8 VGPRs, consumed after S2
    f16x8 vh[2];
    {
        const float* vrow = v + ((size_t)bh*Tc + myIdx)*Dc + hf4*16;
        #pragma unroll
        for (int r = 0; r < 2; r++) {
            float4 a = *(const float4*)(vrow + r*8);
            float4 b = *(const float4*)(vrow + r*8 + 4);
            f16x8 hv = {(h16)a.x,(h16)a.y,(h16)a.z,(h16)a.w,
                        (h16)b.x,(h16)b.y,(h16)b.z,(h16)b.w};
            vh[r] = hv;
        }
    }

    // A2: S = Q.Q^T  (rows [16w,16w+16) x all 128 cols)
    f32x4 accS[8];
    #pragma unroll
    for (int nt = 0; nt < 8; nt++)
        #pragma unroll
        for (int e = 0; e < 4; e++) accS[nt][e] = 0.f;
    #pragma unroll
    for (int k0 = 0; k0 < 64; k0 += 32) {
        f16x8 a = *(const f16x8*)&qv[(i0 + lj)*72 + k0 + quad*8];
        #pragma unroll
        for (int nt = 0; nt < 8; nt++) {
            f16x8 bf = *(const f16x8*)&qv[(nt*16 + lj)*72 + k0 + quad*8];
            accS[nt] = MFMA16(a, bf, accS[nt]);
        }
    }
    __syncthreads();   // S2: all qv(q) reads done -> region reusable for v^T

    #pragma unroll
    for (int nt = 0; nt < 8; nt++) {   // scale + rel (j<=i, else 0) + diag mask
        int j = nt*16 + lj;
        float sj = sinv[j];
        #pragma unroll
        for (int r = 0; r < 4; r++) {
            int i = i0 + quad*4 + r;
            float rl = (j <= i) ? (float)sp[i*136 + j] : 0.f;
            float s = accS[nt][r]*sj + rl;
            accS[nt][r] = (i == j) ? -50000.0f : s;
        }
    }
    #pragma unroll
    for (int r = 0; r < 4; r++) {       // softmax (rows live in 16-lane quads)
        float mx = accS[0][r];
        #pragma unroll
        for (int nt = 1; nt < 8; nt++) mx = fmaxf(mx, accS[nt][r]);
        #pragma unroll
        for (int st = 1; st <= 8; st <<= 1) mx = fmaxf(mx, __shfl_xor(mx, st, 64));
        float sum = 0.f;
        #pragma unroll
        for (int nt = 0; nt < 8; nt++) {
            float e = __expf(accS[nt][r] - mx);
            accS[nt][r] = e; sum += e;
        }
        #pragma unroll
        for (int st = 1; st <= 8; st <<= 1) sum += __shfl_xor(sum, st, 64);
        float inv = 1.0f/sum;
        #pragma unroll
        for (int nt = 0; nt < 8; nt++) accS[nt][r] *= inv;
    }
    #pragma unroll
    for (int nt = 0; nt < 8; nt++)      // write P (f16) to sp (own rows)
        #pragma unroll
        for (int r = 0; r < 4; r++) {
            int i = i0 + quad*4 + r;
            sp[i*136 + nt*16 + lj] = (h16)accS[nt][r];
        }
    {   // store v^T into qv region: vt[d][j], stride 136 (64*136 <= 128*72)
        h16* vt = qv;
        int j = row4, d0 = hf4*16;
        #pragma unroll
        for (int r = 0; r < 2; r++)
            #pragma unroll
            for (int e = 0; e < 8; e++)
                vt[(d0 + r*8 + e)*136 + j] = vh[r][e];
    }
    __syncthreads();   // S3: P + v^T visible

    // O = P.V (K=128)
    f32x4 accO[4];
    #pragma unroll
    for (int nt = 0; nt < 4; nt++)
        #pragma unroll
        for (int e = 0; e < 4; e++) accO[nt][e] = 0.f;
    #pragma unroll
    for (int k0 = 0; k0 < 128; k0 += 32) {
        f16x8 a = *(const f16x8*)&sp[(i0 + lj)*136 + k0 + quad*8];
        #pragma unroll
        for (int nt = 0; nt < 4; nt++) {
            f16x8 bf = *(const f16x8*)&qv[(nt*16 + lj)*136 + k0 + quad*8];
            accO[nt] = MFMA16(a, bf, accO[nt]);
        }
    }
    #pragma unroll
    for (int nt = 0; nt < 4; nt++)
        #pragma unroll
        for (int r = 0; r < 4; r++) {
            int i = i0 + quad*4 + r;
            bo[((size_t)bhc*WSZc + i)*Dc + nt*16 + lj] = accO[nt][r];
        }
}

// ---------------------------------------------------------------------------
// Kernel 4: out[bh,t,:] = (sum of its bo rows + rare ovf) / (cnt+EPS); loss.
// ---------------------------------------------------------------------------
__global__ __launch_bounds__(256) void k_final(const float* __restrict__ bo,
                                               const unsigned short* __restrict__ slots,
                                               const unsigned* __restrict__ cnt,
                                               const int* __restrict__ indices,
                                               const unsigned* __restrict__ aux,
                                               float* __restrict__ out) {
    int row  = blockIdx.x*4 + (threadIdx.x >> 6);   // [0, BH*T)
    int lane = threadIdx.x & 63;
    unsigned c = cnt[row];
    unsigned m = c < MAXPc ? c : MAXPc;
    int bh = row >> 13;
    float acc = 0.f;
    const unsigned short* sl = slots + (size_t)row*MAXPc;
    for (unsigned p = 0; p < m; p++)
        acc += bo[(((size_t)bh << 13) + sl[p])*Dc + lane];
    if (c > MAXPc) {   // astronomically rare
        unsigned n = aux[0]; if (n > OVFCAP) n = OVFCAP;
        int tok = row & 8191;
        for (unsigned q = 0; q < n; q++) {
            unsigned e = aux[2+q];
            if ((int)(e >> 13) == bh && indices[e] == tok)
                acc += bo[(((size_t)bh << 13) + (e & 8191))*Dc + lane];
        }
    }
    out[(size_t)row*Dc + lane] = acc * (1.0f/((float)c + 1e-5f));
    if (row == 0 && lane == 0)
        out[OUT_ELEMS] = ((const float*)aux)[1] * (float)(1e-4 / 16777216.0);
}

extern "C" void kernel_launch(void* const* d_in, const int* in_sizes, int n_in,
                              void* d_out, int out_size, void* d_ws, size_t ws_size,
                              hipStream_t stream) {
    const float* qk    = (const float*)d_in[0];
    const float* v     = (const float*)d_in[1];
    const float* means = (const float*)d_in[2];
    const float* relw  = (const float*)d_in[3];
    float* out = (float*)d_out;
    char*  ws  = (char*)d_ws;

    // workspace layout (bo aliases dists: dists dead after k_topk)
    size_t off = 0;
    float* dists = (float*)(ws + off);
    float* bo    = dists;
    off += (size_t)BHc*NCc*Tc*4;                                           // 64 MB
    int* indices = (int*)(ws + off); off += (size_t)BHc*NCc*WSZc*4;        // 1 MB
    unsigned* cnt = (unsigned*)(ws + off); off += (size_t)BHc*Tc*4;        // 1 MB
    unsigned* aux = (unsigned*)(ws + off); off += (size_t)(2+OVFCAP)*4;    // 16 KB
    unsigned short* slots = (unsigned short*)(ws + off);
    off += (size_t)BHc*Tc*MAXPc*2;                                         // 8 MB
    h16* wh16 = (h16*)(ws + off); off += (size_t)WSZc*Hc*Dc*2;             // 128 KB

    // single memset covers cnt + aux (adjacent)
    hipMemsetAsync(cnt, 0, (size_t)BHc*Tc*4 + (size_t)(2+OVFCAP)*4, stream);

    k_wpack <<<32,           256, 0, stream>>>(relw, wh16);
    k_dists <<<BHc*(Tc/256), 256, 0, stream>>>(qk, means, dists, (float*)aux + 1);
    k_topk  <<<BHc*NCc,      256, 0, stream>>>(dists, indices, cnt, slots, aux);
    k_attn  <<<BHc*NCc,      512, 0, stream>>>(qk, v, wh16, indices, bo);
    k_final <<<BHc*Tc/4,     256, 0, stream>>>(bo, slots, cnt, indices, aux, out);
}

// Round 8
// 363.271 us; speedup vs baseline: 1.0423x; 1.0003x over previous
//
#include <hip/hip_runtime.h>
#include <math.h>

typedef _Float16 h16;
typedef _Float16 f16x8 __attribute__((ext_vector_type(8)));
typedef float f32x4 __attribute__((ext_vector_type(4)));

#define Bc 4
#define Hc 8
#define Tc 8192
#define Dc 64
#define NCc 64
#define WSZc 128
#define BHc (Bc*Hc)
#define MAXPc 16
#define OVFCAP 4095
#define OUT_ELEMS (16777216u)   // B*H*T*D

#define MFMA16(a,b,c) __builtin_amdgcn_mfma_f32_16x16x32_f16(a,b,c,0,0,0)

// ---------------------------------------------------------------------------
// Kernel 0: pack rel_weights[m][h][d] fp32 -> wh16[h][m][d] f16 (128 KB).
// Per-head 16 KB panel, L2/L3-resident, shared by 64 k_attn blocks.
// ---------------------------------------------------------------------------
__global__ __launch_bounds__(256) void k_wpack(const float* __restrict__ relw,
                                               h16* __restrict__ wh16) {
    int idx = blockIdx.x*256 + threadIdx.x;      // [0, 8192): 8 elems each
    int e = idx*8;
    int m = e >> 9, h = (e >> 6) & 7, d = e & 63;
    const float* src = relw + ((size_t)m*Hc + h)*Dc + d;
    float4 a = *(const float4*)src;
    float4 b = *(const float4*)(src + 4);
    f16x8 hv = {(h16)a.x,(h16)a.y,(h16)a.z,(h16)a.w,
                (h16)b.x,(h16)b.y,(h16)b.z,(h16)b.w};
    *(f16x8*)&wh16[((size_t)h*WSZc + m)*Dc + d] = hv;
}

// ---------------------------------------------------------------------------
// Kernel 1: dists[bh][c][t] = dot(l2norm(qk[bh][t]), means[h][c])  (fp32)
// plus commitment-loss raw sum atomically added into loss slot aux[1].
// R8: NO LDS. means read directly from global — the c-loop address is
// wave-uniform -> compiler scalarizes to s_load + v_fmac(v,s,v), freeing the
// LDS pipe (old version: broadcast ds_reads throttled FMA; divergent loss
// gather caused ~64-way bank conflicts, 3.4M cycles).
// ---------------------------------------------------------------------------
__global__ __launch_bounds__(256) void k_dists(const float* __restrict__ qk,
                                               const float* __restrict__ means,
                                               float* __restrict__ dists,
                                               float* __restrict__ loss_acc) {
    __shared__ float red[4];
    int tid = threadIdx.x;
    int blk = blockIdx.x;              // [0, BH*32)
    int bh  = blk >> 5;                // T/256 = 32 chunks per bh
    int chunk = blk & 31;
    int h = bh & (Hc-1);

    const float* mh = means + (size_t)h*NCc*Dc;

    int t = chunk*256 + tid;
    const float* qrow = qk + ((size_t)bh*Tc + t)*Dc;
    float q[Dc];
    #pragma unroll
    for (int d = 0; d < Dc; d += 4) {
        float4 f = *(const float4*)(qrow + d);
        q[d] = f.x; q[d+1] = f.y; q[d+2] = f.z; q[d+3] = f.w;
    }
    float n2 = 0.f;
    #pragma unroll
    for (int d = 0; d < Dc; d++) n2 += q[d]*q[d];
    float nrm = sqrtf(n2);
    if (nrm < 1e-12f) nrm = 1e-12f;
    float inv = 1.0f/nrm;

    float best = -3.4e38f; int bc = 0;
    float* dbase = dists + ((size_t)bh*NCc)*Tc + (size_t)chunk*256 + tid;
    for (int c = 0; c < NCc; c++) {
        float acc = 0.f;
        const float* mc = mh + c*Dc;           // wave-uniform -> s_load path
        #pragma unroll
        for (int d = 0; d < Dc; d++) acc += q[d]*mc[d];
        float dv = acc*inv;
        dbase[(size_t)c*Tc] = dv;
        if (dv > best) { best = dv; bc = c; }   // strict > : first max wins
    }
    float ls = 0.f;
    const float* mb = mh + bc*Dc;              // divergent, L2-hot (16 KB/head)
    #pragma unroll
    for (int d = 0; d < Dc; d++) {
        float diff = q[d]*inv - mb[d];
        ls += diff*diff;
    }
    float lf = ls;
    #pragma unroll
    for (int o = 32; o >= 1; o >>= 1) lf += __shfl_down(lf, o, 64);
    if ((tid & 63) == 0) red[tid >> 6] = lf;
    __syncthreads();
    if (tid == 0) atomicAdd(loss_acc, red[0]+red[1]+red[2]+red[3]);
}

// ---------------------------------------------------------------------------
// Kernel 2: per (bh,c) exact top-128 of 8192 (ties: lower index), sorted asc,
// with the inverse map (cnt/slots/aux) built in the same kernel.
// Keys live in REGISTERS (32/thread) — LDS is hist+scratch only (~18.9 KB).
// ---------------------------------------------------------------------------
__device__ inline unsigned blockScanIncl(unsigned v, volatile unsigned* wsum,
                                         int lane, int wid, unsigned* ptotal) {
    unsigned x = v;
    #pragma unroll
    for (int s = 1; s < 64; s <<= 1) {
        unsigned o = __shfl_up(x, s, 64);
        if (lane >= s) x += o;
    }
    if (lane == 63) wsum[wid] = x;
    __syncthreads();
    unsigned off = 0, tot = 0;
    #pragma unroll
    for (int w2 = 0; w2 < 4; w2++) {
        unsigned s2 = wsum[w2];
        if (w2 < wid) off += s2;
        tot += s2;
    }
    *ptotal = tot;
    return x + off;
}

__global__ __launch_bounds__(256, 6) void k_topk(const float* __restrict__ dists,
                                              int* __restrict__ indices,
                                              unsigned* __restrict__ cnt,
                                              unsigned short* __restrict__ slots,
                                              unsigned* __restrict__ aux) {
    __shared__ unsigned hist[4096];    // 16 KB
    __shared__ unsigned bmap[256];     // 1 KB (8192-bit selection bitmap)
    __shared__ unsigned eqbuf[256];    // 1 KB (tie candidates, rare path)
    __shared__ unsigned wsum[4];
    __shared__ unsigned sh_prefix;
    __shared__ int      sh_k, cnt_eq;

    int tid = threadIdx.x;
    int lane = tid & 63, wid = tid >> 6;
    int bhc = blockIdx.x, bh = bhc >> 6, c = bhc & 63;
    const float* dp = dists + (size_t)bhc*Tc;

    for (int i = tid; i < 4096; i += 256) hist[i] = 0u;
    if (tid == 0) { sh_k = WSZc; sh_prefix = 0u; cnt_eq = 0; }
    bmap[tid] = 0u;
    __syncthreads();

    // load 32 keys/thread into registers (float4-coalesced) + level-0 hist.
    // token for key[ch][j] is  t = ch*1024 + tid*4 + j.
    unsigned key[8][4];
    #pragma unroll
    for (int ch = 0; ch < 8; ch++) {
        float4 f = *(const float4*)(dp + ch*1024 + tid*4);
        float fv[4] = {f.x, f.y, f.z, f.w};
        #pragma unroll
        for (int j = 0; j < 4; j++) {
            unsigned u = __float_as_uint(fv[j]);
            u = (u & 0x80000000u) ? ~u : (u | 0x80000000u);  // order-preserving
            key[ch][j] = u;
            atomicAdd(&hist[u >> 20], 1u);
        }
    }
    __syncthreads();

    unsigned prefix = 0u; int k = WSZc;
    #pragma unroll
    for (int lvl = 0; lvl < 3; lvl++) {
        const int shift   = (lvl == 0) ? 20 : (lvl == 1 ? 8 : 0);
        const int nper    = (lvl == 2) ? 1 : 16;           // bins per thread
        const unsigned nbm = (lvl == 2) ? 255u : 4095u;    // bin mask
        if (lvl > 0) {
            // build filtered histogram for this level (register sweep)
            const unsigned maskH = (lvl == 1) ? 0xFFF00000u : 0xFFFFFF00u;
            for (int i = tid; i <= (int)nbm; i += 256) hist[i] = 0u;
            __syncthreads();
            #pragma unroll
            for (int ch = 0; ch < 8; ch++)
                #pragma unroll
                for (int j = 0; j < 4; j++) {
                    unsigned ky = key[ch][j];
                    if ((ky & maskH) == prefix)
                        atomicAdd(&hist[(ky >> shift) & nbm], 1u);
                }
            __syncthreads();
        }
        // parallel crossing-bin search (suffix = total - excl_ascending)
        int tBase = tid*nper;
        unsigned psum = 0;
        for (int i = 0; i < nper; i++) psum += hist[tBase + i];
        unsigned total;
        unsigned incl = blockScanIncl(psum, wsum, lane, wid, &total);
        unsigned beyond = total - incl;          // keys in bins strictly above
        unsigned suff   = beyond + psum;
        if (beyond < (unsigned)k && (unsigned)k <= suff) {
            unsigned run = beyond;
            for (int i = nper - 1; i >= 0; i--) {
                unsigned hb = hist[tBase + i];
                run += hb;
                if (run >= (unsigned)k) {
                    sh_prefix = prefix | ((unsigned)(tBase + i) << shift);
                    sh_k = k - (int)(run - hb);
                    break;
                }
            }
        }
        __syncthreads();
        prefix = sh_prefix; k = sh_k;
        __syncthreads();
    }
    unsigned Kthr = prefix;    // exact 32-bit threshold key
    int kEq = k;               // # of threshold-equal keys to take (lowest idx)

    // collect: strict-greater -> bitmap; equal -> eqbuf (register sweep)
    #pragma unroll
    for (int ch = 0; ch < 8; ch++)
        #pragma unroll
        for (int j = 0; j < 4; j++) {
            unsigned ky = key[ch][j];
            int t = ch*1024 + tid*4 + j;
            if (ky > Kthr) atomicOr(&bmap[t >> 5], 1u << (t & 31));
            else if (ky == Kthr) {
                int p = atomicAdd(&cnt_eq, 1);
                if (p < 256) eqbuf[p] = (unsigned)t;
            }
        }
    __syncthreads();
    if (cnt_eq == kEq) {       // common path: every equal key is selected
        if (tid < kEq) {
            unsigned t = eqbuf[tid];
            atomicOr(&bmap[t >> 5], 1u << (t & 31));
        }
    } else {                   // rare: sort ties, take lowest kEq indices
        int ce = cnt_eq < 256 ? cnt_eq : 256;
        if (tid >= ce) eqbuf[tid] = 0xFFFFFFFFu;
        __syncthreads();
        for (int k2 = 2; k2 <= 256; k2 <<= 1) {
            for (int j = k2 >> 1; j >= 1; j >>= 1) {
                int i = tid, ixj = i ^ j;
                if (ixj > i) {
                    bool up = ((i & k2) == 0);
                    unsigned a = eqbuf[i], b = eqbuf[ixj];
                    if ((a > b) == up) { eqbuf[i] = b; eqbuf[ixj] = a; }
                }
                __syncthreads();
            }
        }
        if (tid < kEq) {
            unsigned t = eqbuf[tid];
            atomicOr(&bmap[t >> 5], 1u << (t & 31));
        }
    }
    __syncthreads();

    // rank via popcount prefix: indices come out sorted ascending by token
    unsigned w = bmap[tid];
    int pc = __popc(w);
    unsigned total2;
    unsigned incl2 = blockScanIncl((unsigned)pc, wsum, lane, wid, &total2);
    int pos = (int)(incl2 - pc);     // exclusive prefix = output position
    while (w) {
        int b = __ffs(w) - 1; w &= w - 1;
        int t = tid*32 + b;
        indices[(size_t)bhc*WSZc + pos] = t;
        // fused inverse map
        unsigned row = ((unsigned)bh << 13) + (unsigned)t;
        unsigned p2 = atomicAdd(&cnt[row], 1u);
        if (p2 < MAXPc) slots[(size_t)row*MAXPc + p2] = (unsigned short)(c*128 + pos);
        else {
            unsigned o = atomicAdd(&aux[0], 1u);
            if (o < OVFCAP) aux[2+o] = (unsigned)(bhc*WSZc + pos);
        }
        pos++;
    }
}

// ---------------------------------------------------------------------------
// Kernel 3: per (bh,c) fused attention via f16 MFMA (16x16x32).
// 512 threads, 8 waves, 16 ROWS/WAVE (R7 verified no-spill: WRITE=65.5MB,
// VGPR 60, occ 37%). (512,4): cap 128 incl AGPR -> 2 blocks/CU = 16 waves.
// Wave w owns rows [16w, 16w+16). shift(rel)[i][j] = rel[i][127+j-i], j<=i.
// ---------------------------------------------------------------------------
__global__ __launch_bounds__(512, 4) void k_attn(const float* __restrict__ qk,
                                                 const float* __restrict__ v,
                                                 const h16* __restrict__ wh16,
                                                 const int* __restrict__ indices,
                                                 float* __restrict__ bo) {
    __shared__ __align__(16) h16 qv[128*72];      // 18432 B: q f16, later v^T[64][136]
    __shared__ __align__(16) h16 sp[128*136];     // 34816 B: rel scatter, then P
    __shared__ float sinv[128];

    int tid = threadIdx.x;                        // 0..511
    int bid = blockIdx.x;
    int bhc = ((bid & 7) << 8) | (bid >> 3);      // XCD-chunked (bijective, 2048=8*256)
    int bh = bhc >> 6, h = bh & (Hc-1);
    int lane = tid & 63, wid = tid >> 6;          // wid 0..7
    int quad = lane >> 4, lj = lane & 15;
    int i0 = wid*16;

    // staging role: 4 threads per row, 16 floats each
    int row4 = tid >> 2, hf4 = tid & 3;
    int myIdx = indices[(size_t)bhc*WSZc + row4];

    {   // stage q (gathered) fp32->f16; sinv on the fly
        const float* qrow = qk + ((size_t)bh*Tc + myIdx)*Dc + hf4*16;
        float n2 = 0.f;
        #pragma unroll
        for (int k8 = 0; k8 < 2; k8++) {
            float4 a = *(const float4*)(qrow + k8*8);
            float4 b = *(const float4*)(qrow + k8*8 + 4);
            n2 += a.x*a.x + a.y*a.y + a.z*a.z + a.w*a.w
                + b.x*b.x + b.y*b.y + b.z*b.z + b.w*b.w;
            f16x8 hq = {(h16)a.x,(h16)a.y,(h16)a.z,(h16)a.w,
                        (h16)b.x,(h16)b.y,(h16)b.z,(h16)b.w};
            *(f16x8*)&qv[row4*72 + hf4*16 + k8*8] = hq;
        }
        n2 += __shfl_xor(n2, 1, 64);
        n2 += __shfl_xor(n2, 2, 64);
        if (hf4 == 0) {
            float nr = sqrtf(n2); if (nr < 1e-12f) nr = 1e-12f;
            sinv[row4] = 0.125f / nr;
        }
    }
    __syncthreads();   // B1: q + sinv visible

    // A1: REL[i][m] = q_i . w_m (K=64), w from pre-packed f16 panel (L2-hot).
    // Rows [16w,16w+16): only nt >= 7-w produce any j>=0.
    int ntMin = 7 - wid;
    {
        f32x4 accR[8];
        #pragma unroll
        for (int nt = 0; nt < 8; nt++)
            #pragma unroll
            for (int e = 0; e < 4; e++) accR[nt][e] = 0.f;
        const h16* whp = wh16 + (size_t)h*WSZc*Dc;   // [m][d] f16
        #pragma unroll
        for (int k0 = 0; k0 < 64; k0 += 32) {
            f16x8 a = *(const f16x8*)&qv[(i0 + lj)*72 + k0 + quad*8];
            #pragma unroll
            for (int nt = 0; nt < 8; nt++) {
                if (nt < ntMin) continue;          // wave-uniform skip
                f16x8 bf = *(const f16x8*)&whp[(size_t)(nt*16 + lj)*Dc + k0 + quad*8];
                accR[nt] = MFMA16(a, bf, accR[nt]);
            }
        }
        // scatter *0.125 into sp[i][m-127+i]; covers exactly j in [0, i] (own rows)
        #pragma unroll
        for (int nt = 0; nt < 8; nt++) {
            if (nt < ntMin) continue;
            #pragma unroll
            for (int r = 0; r < 4; r++) {
                int i = i0 + quad*4 + r;
                int j = nt*16 + lj - 127 + i;
                if (j >= 0) sp[i*136 + j] = (h16)(accR[nt][r] * 0.125f);
            }
        }
    }

    // prefetch v rows (gathered) as f16 — 8 VGPRs, consumed after S2
    f16x8 vh[2];
    {
        const float* vrow = v + ((size_t)bh*Tc + myIdx)*Dc + hf4*16;
        #pragma unroll
        for (int r = 0; r < 2; r++) {
            float4 a = *(const float4*)(vrow + r*8);
            float4 b = *(const float4*)(vrow + r*8 + 4);
            f16x8 hv = {(h16)a.x,(h16)a.y,(h16)a.z,(h16)a.w,
                        (h16)b.x,(h16)b.y,(h16)b.z,(h16)b.w};
            vh[r] = hv;
        }
    }

    // A2: S = Q.Q^T  (rows [16w,16w+16) x all 128 cols)
    f32x4 accS[8];
    #pragma unroll
    for (int nt = 0; nt < 8; nt++)
        #pragma unroll
        for (int e = 0; e < 4; e++) accS[nt][e] = 0.f;
    #pragma unroll
    for (int k0 = 0; k0 < 64; k0 += 32) {
        f16x8 a = *(const f16x8*)&qv[(i0 + lj)*72 + k0 + quad*8];
        #pragma unroll
        for (int nt = 0; nt < 8; nt++) {
            f16x8 bf = *(const f16x8*)&qv[(nt*16 + lj)*72 + k0 + quad*8];
            accS[nt] = MFMA16(a, bf, accS[nt]);
        }
    }
    __syncthreads();   // S2: all qv(q) reads done -> region reusable for v^T

    #pragma unroll
    for (int nt = 0; nt < 8; nt++) {   // scale + rel (j<=i, else 0) + diag mask
        int j = nt*16 + lj;
        float sj = sinv[j];
        #pragma unroll
        for (int r = 0; r < 4; r++) {
            int i = i0 + quad*4 + r;
            float rl = (j <= i) ? (float)sp[i*136 + j] : 0.f;
            float s = accS[nt][r]*sj + rl;
            accS[nt][r] = (i == j) ? -50000.0f : s;
        }
    }
    #pragma unroll
    for (int r = 0; r < 4; r++) {       // softmax (rows live in 16-lane quads)
        float mx = accS[0][r];
        #pragma unroll
        for (int nt = 1; nt < 8; nt++) mx = fmaxf(mx, accS[nt][r]);
        #pragma unroll
        for (int st = 1; st <= 8; st <<= 1) mx = fmaxf(mx, __shfl_xor(mx, st, 64));
        float sum = 0.f;
        #pragma unroll
        for (int nt = 0; nt < 8; nt++) {
            float e = __expf(accS[nt][r] - mx);
            accS[nt][r] = e; sum += e;
        }
        #pragma unroll
        for (int st = 1; st <= 8; st <<= 1) sum += __shfl_xor(sum, st, 64);
        float inv = 1.0f/sum;
        #pragma unroll
        for (int nt = 0; nt < 8; nt++) accS[nt][r] *= inv;
    }
    #pragma unroll
    for (int nt = 0; nt < 8; nt++)      // write P (f16) to sp (own rows)
        #pragma unroll
        for (int r = 0; r < 4; r++) {
            int i = i0 + quad*4 + r;
            sp[i*136 + nt*16 + lj] = (h16)accS[nt][r];
        }
    {   // store v^T into qv region: vt[d][j], stride 136 (64*136 <= 128*72)
        h16* vt = qv;
        int j = row4, d0 = hf4*16;
        #pragma unroll
        for (int r = 0; r < 2; r++)
            #pragma unroll
            for (int e = 0; e < 8; e++)
                vt[(d0 + r*8 + e)*136 + j] = vh[r][e];
    }
    __syncthreads();   // S3: P + v^T visible

    // O = P.V (K=128)
    f32x4 accO[4];
    #pragma unroll
    for (int nt = 0; nt < 4; nt++)
        #pragma unroll
        for (int e = 0; e < 4; e++) accO[nt][e] = 0.f;
    #pragma unroll
    for (int k0 = 0; k0 < 128; k0 += 32) {
        f16x8 a = *(const f16x8*)&sp[(i0 + lj)*136 + k0 + quad*8];
        #pragma unroll
        for (int nt = 0; nt < 4; nt++) {
            f16x8 bf = *(const f16x8*)&qv[(nt*16 + lj)*136 + k0 + quad*8];
            accO[nt] = MFMA16(a, bf, accO[nt]);
        }
    }
    #pragma unroll
    for (int nt = 0; nt < 4; nt++)
        #pragma unroll
        for (int r = 0; r < 4; r++) {
            int i = i0 + quad*4 + r;
            bo[((size_t)bhc*WSZc + i)*Dc + nt*16 + lj] = accO[nt][r];
        }
}

// ---------------------------------------------------------------------------
// Kernel 4: out[bh,t,:] = (sum of its bo rows + rare ovf) / (cnt+EPS); loss.
// ---------------------------------------------------------------------------
__global__ __launch_bounds__(256) void k_final(const float* __restrict__ bo,
                                               const unsigned short* __restrict__ slots,
                                               const unsigned* __restrict__ cnt,
                                               const int* __restrict__ indices,
                                               const unsigned* __restrict__ aux,
                                               float* __restrict__ out) {
    int row  = blockIdx.x*4 + (threadIdx.x >> 6);   // [0, BH*T)
    int lane = threadIdx.x & 63;
    unsigned c = cnt[row];
    unsigned m = c < MAXPc ? c : MAXPc;
    int bh = row >> 13;
    float acc = 0.f;
    const unsigned short* sl = slots + (size_t)row*MAXPc;
    for (unsigned p = 0; p < m; p++)
        acc += bo[(((size_t)bh << 13) + sl[p])*Dc + lane];
    if (c > MAXPc) {   // astronomically rare
        unsigned n = aux[0]; if (n > OVFCAP) n = OVFCAP;
        int tok = row & 8191;
        for (unsigned q = 0; q < n; q++) {
            unsigned e = aux[2+q];
            if ((int)(e >> 13) == bh && indices[e] == tok)
                acc += bo[(((size_t)bh << 13) + (e & 8191))*Dc + lane];
        }
    }
    out[(size_t)row*Dc + lane] = acc * (1.0f/((float)c + 1e-5f));
    if (row == 0 && lane == 0)
        out[OUT_ELEMS] = ((const float*)aux)[1] * (float)(1e-4 / 16777216.0);
}

extern "C" void kernel_launch(void* const* d_in, const int* in_sizes, int n_in,
                              void* d_out, int out_size, void* d_ws, size_t ws_size,
                              hipStream_t stream) {
    const float* qk    = (const float*)d_in[0];
    const float* v     = (const float*)d_in[1];
    const float* means = (const float*)d_in[2];
    const float* relw  = (const float*)d_in[3];
    float* out = (float*)d_out;
    char*  ws  = (char*)d_ws;

    // workspace layout (bo aliases dists: dists dead after k_topk)
    size_t off = 0;
    float* dists = (float*)(ws + off);
    float* bo    = dists;
    off += (size_t)BHc*NCc*Tc*4;                                           // 64 MB
    int* indices = (int*)(ws + off); off += (size_t)BHc*NCc*WSZc*4;        // 1 MB
    unsigned* cnt = (unsigned*)(ws + off); off += (size_t)BHc*Tc*4;        // 1 MB
    unsigned* aux = (unsigned*)(ws + off); off += (size_t)(2+OVFCAP)*4;    // 16 KB
    unsigned short* slots = (unsigned short*)(ws + off);
    off += (size_t)BHc*Tc*MAXPc*2;                                         // 8 MB
    h16* wh16 = (h16*)(ws + off); off += (size_t)WSZc*Hc*Dc*2;             // 128 KB

    // single memset covers cnt + aux (adjacent)
    hipMemsetAsync(cnt, 0, (size_t)BHc*Tc*4 + (size_t)(2+OVFCAP)*4, stream);

    k_wpack <<<32,           256, 0, stream>>>(relw, wh16);
    k_dists <<<BHc*(Tc/256), 256, 0, stream>>>(qk, means, dists, (float*)aux + 1);
    k_topk  <<<BHc*NCc,      256, 0, stream>>>(dists, indices, cnt, slots, aux);
    k_attn  <<<BHc*NCc,      512, 0, stream>>>(qk, v, wh16, indices, bo);
    k_final <<<BHc*Tc/4,     256, 0, stream>>>(bo, slots, cnt, indices, aux, out);
}